// Round 1
// baseline (635.439 us; speedup 1.0000x reference)
//
#include <hip/hip_runtime.h>

typedef float f32x4 __attribute__((ext_vector_type(4)));
typedef __bf16 bf16x8 __attribute__((ext_vector_type(8)));
typedef unsigned short u16;

__device__ __forceinline__ u16 f2bf(float f) {
  unsigned int u = __builtin_bit_cast(unsigned int, f);
  u += 0x7FFFu + ((u >> 16) & 1u);
  return (u16)(u >> 16);
}

__device__ __forceinline__ void gload16(const void* g, void* l) {
  __builtin_amdgcn_global_load_lds(
      (const __attribute__((address_space(1))) unsigned int*)g,
      (__attribute__((address_space(3))) unsigned int*)l, 16, 0, 0);
}

// ---------------- router: logits, softmax, top-1, Pi/lse2 partials ----------------
__global__ __launch_bounds__(256) void kRouter(
    const float* __restrict__ x, const float* __restrict__ Wr,
    int* __restrict__ tok_e, float* __restrict__ tok_p,
    float* __restrict__ partials /* [9][2048] */) {
  __shared__ float wr[8192];
  __shared__ float red[4][12];
  int tid = threadIdx.x;
#pragma unroll
  for (int i = 0; i < 8; ++i)
    *(float4*)&wr[tid * 4 + i * 1024] = *(const float4*)&Wr[tid * 4 + i * 1024];
  __syncthreads();
  int w = tid >> 6, lane = tid & 63;
  int t = blockIdx.x * 4 + w;
  const float* xp = x + (size_t)t * 1024;
  float acc[8];
#pragma unroll
  for (int e = 0; e < 8; ++e) acc[e] = 0.f;
#pragma unroll
  for (int i = 0; i < 8; ++i) {
    float2 xv = *(const float2*)&xp[i * 128 + lane * 2];
#pragma unroll
    for (int e = 0; e < 8; ++e) {
      float2 wv = *(const float2*)&wr[e * 1024 + i * 128 + lane * 2];
      acc[e] += xv.x * wv.x + xv.y * wv.y;
    }
  }
#pragma unroll
  for (int off = 32; off; off >>= 1) {
#pragma unroll
    for (int e = 0; e < 8; ++e) acc[e] += __shfl_xor(acc[e], off, 64);
  }
  // all lanes hold the 8 logits now
  int bi = 0;
  float m = acc[0];
#pragma unroll
  for (int e = 1; e < 8; ++e)
    if (acc[e] > m) { m = acc[e]; bi = e; }   // first-max ties like argmax
  float ex[8], s = 0.f;
#pragma unroll
  for (int e = 0; e < 8; ++e) { ex[e] = expf(acc[e] - m); s += ex[e]; }
  float inv = 1.f / s;              // == top1 prob (exp(0)/s)
  float lse = m + logf(s);
  if (lane == 0) {
    tok_e[t] = bi;
    tok_p[t] = inv;
#pragma unroll
    for (int e = 0; e < 8; ++e) red[w][e] = ex[e] * inv;
    red[w][8] = lse * lse;
  }
  __syncthreads();
  if (tid < 9) {
    float v = red[0][tid] + red[1][tid] + red[2][tid] + red[3][tid];
    partials[tid * 2048 + blockIdx.x] = v;
  }
}

// ---------------- exact token-order scan + capacity + aux loss ----------------
__global__ __launch_bounds__(256) void kScan(
    const int* __restrict__ tok_e, const float* __restrict__ tok_p,
    const float* __restrict__ partials,
    int* __restrict__ tok_row, int* __restrict__ row2tok,
    float* __restrict__ row_prob, int* __restrict__ cnt_arr,
    float* __restrict__ aux_out) {
  __shared__ int sc[8][256];
  __shared__ float fr[256];
  __shared__ int tot[8];
  __shared__ float ps[9];
  int tid = threadIdx.x;
  int base = tid * 32;
  int lc[8];
#pragma unroll
  for (int e = 0; e < 8; ++e) lc[e] = 0;
  for (int j = 0; j < 32; ++j) lc[tok_e[base + j]]++;
#pragma unroll
  for (int e = 0; e < 8; ++e) sc[e][tid] = lc[e];
  __syncthreads();
  for (int s = 1; s < 256; s <<= 1) {
    int v[8];
#pragma unroll
    for (int e = 0; e < 8; ++e) v[e] = (tid >= s) ? sc[e][tid - s] : 0;
    __syncthreads();
#pragma unroll
    for (int e = 0; e < 8; ++e) sc[e][tid] += v[e];
    __syncthreads();
  }
  if (tid < 8) {
    tot[tid] = sc[tid][255];
    cnt_arr[tid] = min(sc[tid][255], 1024);
  }
  // reduce Pi (8) + lse^2 (1) partials: [9][2048]
  for (int c = 0; c < 9; ++c) {
    float sl = 0.f;
    for (int i = tid; i < 2048; i += 256) sl += partials[c * 2048 + i];
    fr[tid] = sl;
    __syncthreads();
    for (int s2 = 128; s2; s2 >>= 1) {
      if (tid < s2) fr[tid] += fr[tid + s2];
      __syncthreads();
    }
    if (tid == 0) ps[c] = fr[0];
    __syncthreads();
  }
  if (tid == 0) {
    float dot = 0.f;
#pragma unroll
    for (int e = 0; e < 8; ++e)
      dot += ((float)tot[e] / 8192.f) * (ps[e] / 8192.f);
    aux_out[0] = 0.01f * 8.f * dot + 0.001f * (ps[8] / 8192.f);
  }
  int run[8];
#pragma unroll
  for (int e = 0; e < 8; ++e) run[e] = sc[e][tid] - lc[e];  // exclusive prefix
  for (int j = 0; j < 32; ++j) {
    int t = base + j;
    int e = tok_e[t];
    int p = run[e]++;
    if (p < 1024) {
      int row = e * 1024 + p;
      tok_row[t] = row;
      row2tok[row] = t;
      row_prob[row] = tok_p[t];
    } else {
      tok_row[t] = -1;
    }
  }
}

// ---------------- dispatch (bf16) + pass-through for dropped tokens ----------------
__global__ __launch_bounds__(256) void kDispatch(
    const float* __restrict__ x, const int* __restrict__ tok_row,
    u16* __restrict__ Xd, float* __restrict__ y) {
  int t = blockIdx.x, tid = threadIdx.x;
  int row = tok_row[t];
  float4 v = *(const float4*)&x[(size_t)t * 1024 + tid * 4];
  if (row >= 0) {
    ushort4 o;
    o.x = f2bf(v.x); o.y = f2bf(v.y); o.z = f2bf(v.z); o.w = f2bf(v.w);
    *(ushort4*)&Xd[(size_t)row * 1024 + tid * 4] = o;
  } else {
    *(float4*)&y[(size_t)t * 1024 + tid * 4] = v;
  }
}

// ---------------- transpose + fp32->bf16: [E][K][N] -> [E][N][K] ----------------
__global__ __launch_bounds__(256) void kTransConv(
    const float* __restrict__ src, u16* __restrict__ dst, int K, int N) {
  __shared__ u16 tl[64 * 66];
  int e = blockIdx.z;
  int n0 = blockIdx.x * 64, k0 = blockIdx.y * 64;
  src += (size_t)e * K * N;
  dst += (size_t)e * N * K;
  int tid = threadIdx.x;
  int rk = tid >> 4;
  int rn = (tid & 15) * 4;
#pragma unroll
  for (int j = 0; j < 4; ++j) {
    int k = rk + j * 16;
    float4 v = *(const float4*)&src[(size_t)(k0 + k) * N + n0 + rn];
    tl[(rn + 0) * 66 + k] = f2bf(v.x);
    tl[(rn + 1) * 66 + k] = f2bf(v.y);
    tl[(rn + 2) * 66 + k] = f2bf(v.z);
    tl[(rn + 3) * 66 + k] = f2bf(v.w);
  }
  __syncthreads();
  int f = tid >> 2;
  int seg = (tid & 3) * 16;
  uint4 tv[2];
  u16* tp = (u16*)tv;
#pragma unroll
  for (int i = 0; i < 16; ++i) tp[i] = tl[f * 66 + seg + i];
  *(uint4*)&dst[(size_t)(n0 + f) * K + k0 + seg] = tv[0];
  *(uint4*)&dst[(size_t)(n0 + f) * K + k0 + seg + 8] = tv[1];
}

// ---------------- grouped TN GEMM, 128x128 tile, BK=32, m97 structure ----------------
// MODE 1: H = relu(A@B^T + b1) stored bf16.  MODE 2: y[tok] = prob*(A@B^T + b2) scatter.
template <int MODE>
__global__ __launch_bounds__(256) void kGemm(
    const u16* __restrict__ A, const u16* __restrict__ B,
    const float* __restrict__ bias,
    u16* __restrict__ Hout, float* __restrict__ Yout,
    const int* __restrict__ cnt_arr, const int* __restrict__ row2tok,
    const float* __restrict__ row_prob, int K, int N) {
  int e = blockIdx.z, mt = blockIdx.y, nt = blockIdx.x;
  int cnt = cnt_arr[e];
  if (mt * 128 >= cnt) return;
  __shared__ u16 As[128 * 32];
  __shared__ u16 Bs[128 * 32];
  int tid = threadIdx.x, lane = tid & 63, w = tid >> 6;
  int wr = w >> 1, wc = w & 1, lrow = lane & 15, kg = lane >> 4;
  const u16* Ab = A + (size_t)(e * 1024 + mt * 128) * K;
  const u16* Bb = B + (size_t)e * N * K + (size_t)(nt * 128) * K;
  f32x4 acc[4][4];
#pragma unroll
  for (int i = 0; i < 4; ++i)
#pragma unroll
    for (int j = 0; j < 4; ++j) acc[i][j] = (f32x4)0.f;
  int i0 = (w * 2) * 64 + lane;
  int i1 = i0 + 64;
  int r0 = i0 >> 2, ks0 = (i0 & 3) * 8;
  int r1 = i1 >> 2, ks1 = (i1 & 3) * 8;
  for (int k0 = 0; k0 < K; k0 += 32) {
    gload16(Ab + (size_t)r0 * K + k0 + ks0, &As[i0 * 8]);
    gload16(Ab + (size_t)r1 * K + k0 + ks1, &As[i1 * 8]);
    gload16(Bb + (size_t)r0 * K + k0 + ks0, &Bs[i0 * 8]);
    gload16(Bb + (size_t)r1 * K + k0 + ks1, &Bs[i1 * 8]);
    __syncthreads();
    bf16x8 a[4], b[4];
#pragma unroll
    for (int mi = 0; mi < 4; ++mi)
      a[mi] = *(const bf16x8*)&As[(wr * 64 + mi * 16 + lrow) * 32 + kg * 8];
#pragma unroll
    for (int ni = 0; ni < 4; ++ni)
      b[ni] = *(const bf16x8*)&Bs[(wc * 64 + ni * 16 + lrow) * 32 + kg * 8];
#pragma unroll
    for (int mi = 0; mi < 4; ++mi)
#pragma unroll
      for (int ni = 0; ni < 4; ++ni)
        acc[mi][ni] = __builtin_amdgcn_mfma_f32_16x16x32_bf16(
            a[mi], b[ni], acc[mi][ni], 0, 0, 0);
    __syncthreads();
  }
  int n0 = nt * 128;
  if (MODE == 1) {
#pragma unroll
    for (int ni = 0; ni < 4; ++ni) {
      int col = n0 + wc * 64 + ni * 16 + lrow;
      float bv = bias[e * N + col];
#pragma unroll
      for (int mi = 0; mi < 4; ++mi)
#pragma unroll
        for (int j = 0; j < 4; ++j) {
          int rl = wr * 64 + mi * 16 + kg * 4 + j;
          float v = fmaxf(acc[mi][ni][j] + bv, 0.f);
          Hout[(size_t)(e * 1024 + mt * 128 + rl) * N + col] = f2bf(v);
        }
    }
  } else {
    int cols[4];
    float bv[4];
#pragma unroll
    for (int ni = 0; ni < 4; ++ni) {
      cols[ni] = n0 + wc * 64 + ni * 16 + lrow;
      bv[ni] = bias[e * N + cols[ni]];
    }
#pragma unroll
    for (int mi = 0; mi < 4; ++mi)
#pragma unroll
      for (int j = 0; j < 4; ++j) {
        int rl = wr * 64 + mi * 16 + kg * 4 + j;
        int rie = mt * 128 + rl;
        if (rie < cnt) {
          int grow = e * 1024 + rie;
          int tt = row2tok[grow];
          float pp = row_prob[grow];
          float* yr = Yout + (size_t)tt * 1024;
#pragma unroll
          for (int ni = 0; ni < 4; ++ni)
            yr[cols[ni]] = pp * (acc[mi][ni][j] + bv[ni]);
        }
      }
  }
}

extern "C" void kernel_launch(void* const* d_in, const int* in_sizes, int n_in,
                              void* d_out, int out_size, void* d_ws, size_t ws_size,
                              hipStream_t stream) {
  (void)in_sizes; (void)n_in; (void)out_size; (void)ws_size;
  const float* x  = (const float*)d_in[0];
  const float* Wr = (const float*)d_in[1];
  const float* W1 = (const float*)d_in[2];
  const float* b1 = (const float*)d_in[3];
  const float* W2 = (const float*)d_in[4];
  const float* b2 = (const float*)d_in[5];
  float* y = (float*)d_out;
  char* ws = (char*)d_ws;
  // ws layout (bytes)
  u16*   W1T      = (u16*)(ws);                    // 8*4096*1024*2 = 64 MiB  [E][N][K]
  u16*   W2T      = (u16*)(ws + 67108864);         // 64 MiB                  [E][N][K]
  u16*   Xd       = (u16*)(ws + 134217728);        // 8192*1024*2 = 16 MiB
  u16*   H        = (u16*)(ws + 150994944);        // 8192*4096*2 = 64 MiB
  int*   tok_e    = (int*)(ws + 218103808);
  float* tok_p    = (float*)(ws + 218136576);
  int*   tok_row  = (int*)(ws + 218169344);
  int*   row2tok  = (int*)(ws + 218202112);
  float* row_prob = (float*)(ws + 218234880);
  int*   cnt_arr  = (int*)(ws + 218267648);
  float* partials = (float*)(ws + 218267776);      // 9*2048 floats

  kRouter<<<2048, 256, 0, stream>>>(x, Wr, tok_e, tok_p, partials);
  kScan<<<1, 256, 0, stream>>>(tok_e, tok_p, partials, tok_row, row2tok,
                               row_prob, cnt_arr, y + 8388608);
  kDispatch<<<8192, 256, 0, stream>>>(x, tok_row, Xd, y);
  kTransConv<<<dim3(64, 16, 8), 256, 0, stream>>>(W1, W1T, 1024, 4096);
  kTransConv<<<dim3(16, 64, 8), 256, 0, stream>>>(W2, W2T, 4096, 1024);
  kGemm<1><<<dim3(32, 8, 8), 256, 0, stream>>>(Xd, W1T, b1, H, nullptr,
                                               cnt_arr, nullptr, nullptr, 1024, 4096);
  kGemm<2><<<dim3(8, 8, 8), 256, 0, stream>>>(H, W2T, b2, nullptr, y,
                                              cnt_arr, row2tok, row_prob, 4096, 1024);
}

// Round 6
// 571.512 us; speedup vs baseline: 1.1119x; 1.1119x over previous
//
#include <hip/hip_runtime.h>

typedef float f32x4 __attribute__((ext_vector_type(4)));
typedef __bf16 bf16x8 __attribute__((ext_vector_type(8)));
typedef unsigned short u16;

__device__ __forceinline__ u16 f2bf(float f) {
  unsigned int u = __builtin_bit_cast(unsigned int, f);
  u += 0x7FFFu + ((u >> 16) & 1u);
  return (u16)(u >> 16);
}

__device__ __forceinline__ void gload16(const void* g, void* l) {
  __builtin_amdgcn_global_load_lds(
      (const __attribute__((address_space(1))) unsigned int*)g,
      (__attribute__((address_space(3))) unsigned int*)l, 16, 0, 0);
}

#define BAR()   asm volatile("s_barrier" ::: "memory")
#define LGKM0() asm volatile("s_waitcnt lgkmcnt(0)" ::: "memory")
#define VMCNT6() asm volatile("s_waitcnt vmcnt(6)" ::: "memory")
#define PRIO1 __builtin_amdgcn_s_setprio(1)
#define PRIO0 __builtin_amdgcn_s_setprio(0)

// ---------------- router: logits, softmax, top-1, Pi/lse2 partials ----------------
__global__ __launch_bounds__(256) void kRouter(
    const float* __restrict__ x, const float* __restrict__ Wr,
    int* __restrict__ tok_e, float* __restrict__ tok_p,
    float* __restrict__ partials /* [9][2048] */) {
  __shared__ float wr[8192];
  __shared__ float red[4][12];
  int tid = threadIdx.x;
#pragma unroll
  for (int i = 0; i < 8; ++i)
    *(float4*)&wr[tid * 4 + i * 1024] = *(const float4*)&Wr[tid * 4 + i * 1024];
  __syncthreads();
  int w = tid >> 6, lane = tid & 63;
  int t = blockIdx.x * 4 + w;
  const float* xp = x + (size_t)t * 1024;
  float acc[8];
#pragma unroll
  for (int e = 0; e < 8; ++e) acc[e] = 0.f;
#pragma unroll
  for (int i = 0; i < 8; ++i) {
    float2 xv = *(const float2*)&xp[i * 128 + lane * 2];
#pragma unroll
    for (int e = 0; e < 8; ++e) {
      float2 wv = *(const float2*)&wr[e * 1024 + i * 128 + lane * 2];
      acc[e] += xv.x * wv.x + xv.y * wv.y;
    }
  }
#pragma unroll
  for (int off = 32; off; off >>= 1) {
#pragma unroll
    for (int e = 0; e < 8; ++e) acc[e] += __shfl_xor(acc[e], off, 64);
  }
  int bi = 0;
  float m = acc[0];
#pragma unroll
  for (int e = 1; e < 8; ++e)
    if (acc[e] > m) { m = acc[e]; bi = e; }
  float ex[8], s = 0.f;
#pragma unroll
  for (int e = 0; e < 8; ++e) { ex[e] = expf(acc[e] - m); s += ex[e]; }
  float inv = 1.f / s;
  float lse = m + logf(s);
  if (lane == 0) {
    tok_e[t] = bi;
    tok_p[t] = inv;
#pragma unroll
    for (int e = 0; e < 8; ++e) red[w][e] = ex[e] * inv;
    red[w][8] = lse * lse;
  }
  __syncthreads();
  if (tid < 9) {
    float v = red[0][tid] + red[1][tid] + red[2][tid] + red[3][tid];
    partials[tid * 2048 + blockIdx.x] = v;
  }
}

// ---------------- exact token-order scan + capacity + aux loss ----------------
__global__ __launch_bounds__(256) void kScan(
    const int* __restrict__ tok_e, const float* __restrict__ tok_p,
    const float* __restrict__ partials,
    int* __restrict__ tok_row, int* __restrict__ row2tok,
    float* __restrict__ row_prob, int* __restrict__ cnt_arr,
    float* __restrict__ aux_out) {
  __shared__ int sc[8][256];
  __shared__ float fr[256];
  __shared__ int tot[8];
  __shared__ float ps[9];
  int tid = threadIdx.x;
  int base = tid * 32;
  int lc[8];
#pragma unroll
  for (int e = 0; e < 8; ++e) lc[e] = 0;
  for (int j = 0; j < 32; ++j) lc[tok_e[base + j]]++;
#pragma unroll
  for (int e = 0; e < 8; ++e) sc[e][tid] = lc[e];
  __syncthreads();
  for (int s = 1; s < 256; s <<= 1) {
    int v[8];
#pragma unroll
    for (int e = 0; e < 8; ++e) v[e] = (tid >= s) ? sc[e][tid - s] : 0;
    __syncthreads();
#pragma unroll
    for (int e = 0; e < 8; ++e) sc[e][tid] += v[e];
    __syncthreads();
  }
  if (tid < 8) {
    tot[tid] = sc[tid][255];
    cnt_arr[tid] = min(sc[tid][255], 1024);
  }
  for (int c = 0; c < 9; ++c) {
    float sl = 0.f;
    for (int i = tid; i < 2048; i += 256) sl += partials[c * 2048 + i];
    fr[tid] = sl;
    __syncthreads();
    for (int s2 = 128; s2; s2 >>= 1) {
      if (tid < s2) fr[tid] += fr[tid + s2];
      __syncthreads();
    }
    if (tid == 0) ps[c] = fr[0];
    __syncthreads();
  }
  if (tid == 0) {
    float dot = 0.f;
#pragma unroll
    for (int e = 0; e < 8; ++e)
      dot += ((float)tot[e] / 8192.f) * (ps[e] / 8192.f);
    aux_out[0] = 0.01f * 8.f * dot + 0.001f * (ps[8] / 8192.f);
  }
  int run[8];
#pragma unroll
  for (int e = 0; e < 8; ++e) run[e] = sc[e][tid] - lc[e];
  for (int j = 0; j < 32; ++j) {
    int t = base + j;
    int e = tok_e[t];
    int p = run[e]++;
    if (p < 1024) {
      int row = e * 1024 + p;
      tok_row[t] = row;
      row2tok[row] = t;
      row_prob[row] = tok_p[t];
    } else {
      tok_row[t] = -1;
    }
  }
}

// ---------------- dispatch (bf16) + pass-through for dropped tokens ----------------
__global__ __launch_bounds__(256) void kDispatch(
    const float* __restrict__ x, const int* __restrict__ tok_row,
    u16* __restrict__ Xd, float* __restrict__ y) {
  int t = blockIdx.x, tid = threadIdx.x;
  int row = tok_row[t];
  float4 v = *(const float4*)&x[(size_t)t * 1024 + tid * 4];
  if (row >= 0) {
    ushort4 o;
    o.x = f2bf(v.x); o.y = f2bf(v.y); o.z = f2bf(v.z); o.w = f2bf(v.w);
    *(ushort4*)&Xd[(size_t)row * 1024 + tid * 4] = o;
  } else {
    *(float4*)&y[(size_t)t * 1024 + tid * 4] = v;
  }
}

// ---------------- transpose + fp32->bf16: [E][K][N] -> [E][N][K] ----------------
__global__ __launch_bounds__(256) void kTransConv(
    const float* __restrict__ src, u16* __restrict__ dst, int K, int N) {
  __shared__ u16 tl[64 * 66];
  int e = blockIdx.z;
  int n0 = blockIdx.x * 64, k0 = blockIdx.y * 64;
  src += (size_t)e * K * N;
  dst += (size_t)e * N * K;
  int tid = threadIdx.x;
  int rk = tid >> 4;
  int rn = (tid & 15) * 4;
#pragma unroll
  for (int j = 0; j < 4; ++j) {
    int k = rk + j * 16;
    float4 v = *(const float4*)&src[(size_t)(k0 + k) * N + n0 + rn];
    tl[(rn + 0) * 66 + k] = f2bf(v.x);
    tl[(rn + 1) * 66 + k] = f2bf(v.y);
    tl[(rn + 2) * 66 + k] = f2bf(v.z);
    tl[(rn + 3) * 66 + k] = f2bf(v.w);
  }
  __syncthreads();
  int f = tid >> 2;
  int seg = (tid & 3) * 16;
  uint4 tv[2];
  u16* tp = (u16*)tv;
#pragma unroll
  for (int i = 0; i < 16; ++i) tp[i] = tl[f * 66 + seg + i];
  *(uint4*)&dst[(size_t)(n0 + f) * K + k0 + seg] = tv[0];
  *(uint4*)&dst[(size_t)(n0 + f) * K + k0 + seg + 8] = tv[1];
}

// ---------------- 256x256x64 8-phase grouped TN GEMM (T2+T3+T4+T5) ----------------
// MODE 1: H = relu(A@B^T + b1) bf16.  MODE 2: fp32 partial (split-K=2) to Pout.
// LDS swizzle: slot(row,c16) holds global chunk (c16 ^ (row&7)); read at
// c16' = c16 ^ (row&7). Stage: linear dest + pre-swizzled per-lane global src.

#define STA(BUF, U, KK) do {                                                       \
    int ra0_ = (U) * 64 + (tid >> 3);                                              \
    int ra1_ = 128 + ra0_;                                                         \
    gload16(Atb + (size_t)ra0_ * KD + (KK) + csw, &smA[BUF][ra0_ * 64 + dsl]);     \
    gload16(Atb + (size_t)ra1_ * KD + (KK) + csw, &smA[BUF][ra1_ * 64 + dsl]);     \
  } while (0)

#define BROW(RIDX, U) ((((RIDX) >> 5) * 64) + (U) * 32 + ((RIDX) & 31))
#define STB(BUF, U, KK) do {                                                       \
    int rb0_ = BROW(tid >> 3, U);                                                  \
    int rb1_ = BROW(64 + (tid >> 3), U);                                           \
    gload16(Btb + (size_t)rb0_ * KD + (KK) + csw, &smB[BUF][rb0_ * 64 + dsl]);     \
    gload16(Btb + (size_t)rb1_ * KD + (KK) + csw, &smB[BUF][rb1_ * 64 + dsl]);     \
  } while (0)

#define LDA(MB, BUF) do {                                                          \
    _Pragma("unroll") for (int m_ = 0; m_ < 4; ++m_)                               \
    _Pragma("unroll") for (int ks_ = 0; ks_ < 2; ++ks_)                            \
      av[m_][ks_] = *(const bf16x8*)&smA[BUF][(aro + ((MB) + m_) * 16) * 64 + cofs[ks_]]; \
  } while (0)

#define LDB(DST, NB, BUF) do {                                                     \
    _Pragma("unroll") for (int n_ = 0; n_ < 2; ++n_)                               \
    _Pragma("unroll") for (int ks_ = 0; ks_ < 2; ++ks_)                            \
      DST[n_][ks_] = *(const bf16x8*)&smB[BUF][(bro + ((NB) + n_) * 16) * 64 + cofs[ks_]]; \
  } while (0)

#define MFMAQ(MB, BV, NB) do {                                                     \
    _Pragma("unroll") for (int m_ = 0; m_ < 4; ++m_)                               \
    _Pragma("unroll") for (int n_ = 0; n_ < 2; ++n_)                               \
    _Pragma("unroll") for (int ks_ = 0; ks_ < 2; ++ks_)                            \
      acc[(MB) + m_][(NB) + n_] = __builtin_amdgcn_mfma_f32_16x16x32_bf16(         \
          av[m_][ks_], BV[n_][ks_], acc[(MB) + m_][(NB) + n_], 0, 0, 0);           \
  } while (0)

template <int MODE>
__global__ __launch_bounds__(512, 2) void kGemm8(
    const u16* __restrict__ A, const u16* __restrict__ Bw,
    const float* __restrict__ bias, u16* __restrict__ Hout,
    float* __restrict__ Pout, const int* __restrict__ cnt_arr) {
  constexpr int KD = (MODE == 1) ? 1024 : 4096;   // global K stride
  constexpr int ND = (MODE == 1) ? 4096 : 1024;
  constexpr int NT = (MODE == 1) ? 16 : 32;       // K-tiles (64) per block
  __shared__ u16 smA[2][16384];
  __shared__ u16 smB[2][16384];
  const int nt = blockIdx.x;
  const int mt = blockIdx.y;
  const int e  = (MODE == 1) ? blockIdx.z : (blockIdx.z >> 1);
  const int kbase = (MODE == 1) ? 0 : ((blockIdx.z & 1) * 2048);
  const int cnt = cnt_arr[e];
  if (mt * 256 >= cnt) return;
  const int tid = threadIdx.x;
  const int lane = tid & 63, wid = tid >> 6;
  const int wr = wid >> 2, wc = wid & 3;
  const int lrow = lane & 15, kg = lane >> 4;
  const u16* Atb = A + (size_t)(e * 1024 + mt * 256) * KD + kbase;
  const u16* Btb = Bw + (size_t)e * ND * KD + (size_t)(nt * 256) * KD + kbase;
  const int csw = (((tid & 7) ^ ((tid >> 3) & 7))) * 8;  // swizzled src chunk (u16)
  const int dsl = (tid & 7) * 8;                         // linear dest chunk (u16)
  const int aro = wr * 128 + lrow;
  const int bro = wc * 64 + lrow;
  const int sw = lrow & 7;
  const int cofs[2] = { ((0 + kg) ^ sw) * 8, ((4 + kg) ^ sw) * 8 };

  f32x4 acc[8][4];
#pragma unroll
  for (int i = 0; i < 8; ++i)
#pragma unroll
    for (int j = 0; j < 4; ++j) acc[i][j] = (f32x4)0.f;
  bf16x8 av[4][2], b0[2][2], b1[2][2];

  // prologue: tile0 {A-lo,B-lo,B-hi,A-hi}, tile1 {A-lo,B-lo,B-hi} (A-hi at P1)
  STA(0, 0, 0); STB(0, 0, 0); STB(0, 1, 0); STA(0, 1, 0);
  STA(1, 0, 64); STB(1, 0, 64); STB(1, 1, 64);
  VMCNT6();
  BAR();

  for (int i = 0; i < NT / 2; ++i) {
    const int kc1 = (2 * i + 1) * 64;
    const int kn  = (2 * i + 2 < NT) ? (2 * i + 2) * 64 : 0;
    const int kn1 = (2 * i + 3 < NT) ? (2 * i + 3) * 64 : 0;
    // P1
    LDA(0, 0); LDB(b0, 0, 0);
    STA(1, 1, kc1);
    BAR(); LGKM0();
    PRIO1; MFMAQ(0, b0, 0); PRIO0;
    BAR();
    // P2
    LDB(b1, 2, 0);
    STA(0, 0, kn);
    BAR(); LGKM0();
    PRIO1; MFMAQ(0, b1, 2); PRIO0;
    BAR();
    // P3
    LDA(4, 0);
    STB(0, 0, kn);
    BAR(); LGKM0();
    PRIO1; MFMAQ(4, b0, 0); PRIO0;
    BAR();
    // P4
    STB(0, 1, kn);
    VMCNT6();
    BAR();
    PRIO1; MFMAQ(4, b1, 2); PRIO0;
    BAR();
    // P5
    LDA(0, 1); LDB(b0, 0, 1);
    STA(0, 1, kn);
    BAR(); LGKM0();
    PRIO1; MFMAQ(0, b0, 0); PRIO0;
    BAR();
    // P6
    LDB(b1, 2, 1);
    STA(1, 0, kn1);
    BAR(); LGKM0();
    PRIO1; MFMAQ(0, b1, 2); PRIO0;
    BAR();
    // P7
    LDA(4, 1);
    STB(1, 0, kn1);
    BAR(); LGKM0();
    PRIO1; MFMAQ(4, b0, 0); PRIO0;
    BAR();
    // P8
    STB(1, 1, kn1);
    VMCNT6();
    BAR();
    PRIO1; MFMAQ(4, b1, 2); PRIO0;
    BAR();
  }

  const int colb = nt * 256 + wc * 64 + lrow;
  if (MODE == 1) {
    float bv[4];
#pragma unroll
    for (int ni = 0; ni < 4; ++ni) bv[ni] = bias[e * 4096 + colb + ni * 16];
#pragma unroll
    for (int mi = 0; mi < 8; ++mi)
#pragma unroll
      for (int jj = 0; jj < 4; ++jj) {
        size_t rbase = (size_t)(e * 1024 + mt * 256 + wr * 128 + mi * 16 + kg * 4 + jj) * 4096;
#pragma unroll
        for (int ni = 0; ni < 4; ++ni)
          Hout[rbase + colb + ni * 16] = f2bf(fmaxf(acc[mi][ni][jj] + bv[ni], 0.f));
      }
  } else {
    float* P = Pout + (size_t)(blockIdx.z & 1) * 8388608;
#pragma unroll
    for (int mi = 0; mi < 8; ++mi)
#pragma unroll
      for (int jj = 0; jj < 4; ++jj) {
        size_t rbase = (size_t)(e * 1024 + mt * 256 + wr * 128 + mi * 16 + kg * 4 + jj) * 1024;
#pragma unroll
        for (int ni = 0; ni < 4; ++ni)
          P[rbase + colb + ni * 16] = acc[mi][ni][jj];
      }
  }
}

// ---------------- split-K combine: y[tok] = prob*(P0+P1+b2) ----------------
__global__ __launch_bounds__(256) void kCombine(
    const float* __restrict__ P0, const float* __restrict__ P1,
    const float* __restrict__ b2, const int* __restrict__ cnt_arr,
    const int* __restrict__ row2tok, const float* __restrict__ row_prob,
    float* __restrict__ y) {
  int r = blockIdx.x;
  int e = r >> 10, rie = r & 1023;
  if (rie >= cnt_arr[e]) return;
  int tok = row2tok[r];
  float pp = row_prob[r];
  int c = threadIdx.x * 4;
  float4 p0 = *(const float4*)&P0[(size_t)r * 1024 + c];
  float4 p1 = *(const float4*)&P1[(size_t)r * 1024 + c];
  float4 bb = *(const float4*)&b2[e * 1024 + c];
  float4 o;
  o.x = pp * (p0.x + p1.x + bb.x);
  o.y = pp * (p0.y + p1.y + bb.y);
  o.z = pp * (p0.z + p1.z + bb.z);
  o.w = pp * (p0.w + p1.w + bb.w);
  *(float4*)&y[(size_t)tok * 1024 + c] = o;
}

extern "C" void kernel_launch(void* const* d_in, const int* in_sizes, int n_in,
                              void* d_out, int out_size, void* d_ws, size_t ws_size,
                              hipStream_t stream) {
  (void)in_sizes; (void)n_in; (void)out_size; (void)ws_size;
  const float* x  = (const float*)d_in[0];
  const float* Wr = (const float*)d_in[1];
  const float* W1 = (const float*)d_in[2];
  const float* b1 = (const float*)d_in[3];
  const float* W2 = (const float*)d_in[4];
  const float* b2 = (const float*)d_in[5];
  float* y = (float*)d_out;
  char* ws = (char*)d_ws;
  u16*   W1T      = (u16*)(ws);                    // 64 MiB [E][4096][1024]; reused as P after GEMM1
  u16*   W2T      = (u16*)(ws + 67108864);         // 64 MiB [E][1024][4096]
  u16*   Xd       = (u16*)(ws + 134217728);        // 16 MiB
  u16*   H        = (u16*)(ws + 150994944);        // 64 MiB
  int*   tok_e    = (int*)(ws + 218103808);
  float* tok_p    = (float*)(ws + 218136576);
  int*   tok_row  = (int*)(ws + 218169344);
  int*   row2tok  = (int*)(ws + 218202112);
  float* row_prob = (float*)(ws + 218234880);
  int*   cnt_arr  = (int*)(ws + 218267648);
  float* partials = (float*)(ws + 218267776);
  float* Pbuf     = (float*)ws;                    // aliases W1T (dead after GEMM1)

  kRouter<<<2048, 256, 0, stream>>>(x, Wr, tok_e, tok_p, partials);
  kScan<<<1, 256, 0, stream>>>(tok_e, tok_p, partials, tok_row, row2tok,
                               row_prob, cnt_arr, y + 8388608);
  kDispatch<<<8192, 256, 0, stream>>>(x, tok_row, Xd, y);
  kTransConv<<<dim3(64, 16, 8), 256, 0, stream>>>(W1, W1T, 1024, 4096);
  kTransConv<<<dim3(16, 64, 8), 256, 0, stream>>>(W2, W2T, 4096, 1024);
  kGemm8<1><<<dim3(16, 4, 8), 512, 0, stream>>>(Xd, W1T, b1, H, nullptr, cnt_arr);
  kGemm8<2><<<dim3(4, 4, 16), 512, 0, stream>>>(H, W2T, nullptr, nullptr, Pbuf, cnt_arr);
  kCombine<<<8192, 256, 0, stream>>>(Pbuf, Pbuf + 8388608, b2, cnt_arr,
                                     row2tok, row_prob, y);
}

// Round 7
// 570.886 us; speedup vs baseline: 1.1131x; 1.0011x over previous
//
#include <hip/hip_runtime.h>

typedef float f32x4 __attribute__((ext_vector_type(4)));
typedef __bf16 bf16x8 __attribute__((ext_vector_type(8)));
typedef unsigned short u16;

__device__ __forceinline__ u16 f2bf(float f) {
  unsigned int u = __builtin_bit_cast(unsigned int, f);
  u += 0x7FFFu + ((u >> 16) & 1u);
  return (u16)(u >> 16);
}

__device__ __forceinline__ void gload16(const void* g, void* l) {
  __builtin_amdgcn_global_load_lds(
      (const __attribute__((address_space(1))) unsigned int*)g,
      (__attribute__((address_space(3))) unsigned int*)l, 16, 0, 0);
}

#define BAR()   asm volatile("s_barrier" ::: "memory")
#define LGKM0() asm volatile("s_waitcnt lgkmcnt(0)" ::: "memory")
#define VMCNT6() asm volatile("s_waitcnt vmcnt(6)" ::: "memory")
#define PRIO1 __builtin_amdgcn_s_setprio(1)
#define PRIO0 __builtin_amdgcn_s_setprio(0)

// ---------------- router: logits, softmax, top-1, Pi/lse2 partials ----------------
__global__ __launch_bounds__(256) void kRouter(
    const float* __restrict__ x, const float* __restrict__ Wr,
    int* __restrict__ tok_e, float* __restrict__ tok_p,
    float* __restrict__ partials /* [9][2048] */) {
  __shared__ float wr[8192];
  __shared__ float red[4][12];
  int tid = threadIdx.x;
#pragma unroll
  for (int i = 0; i < 8; ++i)
    *(float4*)&wr[tid * 4 + i * 1024] = *(const float4*)&Wr[tid * 4 + i * 1024];
  __syncthreads();
  int w = tid >> 6, lane = tid & 63;
  int t = blockIdx.x * 4 + w;
  const float* xp = x + (size_t)t * 1024;
  float acc[8];
#pragma unroll
  for (int e = 0; e < 8; ++e) acc[e] = 0.f;
#pragma unroll
  for (int i = 0; i < 8; ++i) {
    float2 xv = *(const float2*)&xp[i * 128 + lane * 2];
#pragma unroll
    for (int e = 0; e < 8; ++e) {
      float2 wv = *(const float2*)&wr[e * 1024 + i * 128 + lane * 2];
      acc[e] += xv.x * wv.x + xv.y * wv.y;
    }
  }
#pragma unroll
  for (int off = 32; off; off >>= 1) {
#pragma unroll
    for (int e = 0; e < 8; ++e) acc[e] += __shfl_xor(acc[e], off, 64);
  }
  int bi = 0;
  float m = acc[0];
#pragma unroll
  for (int e = 1; e < 8; ++e)
    if (acc[e] > m) { m = acc[e]; bi = e; }
  float ex[8], s = 0.f;
#pragma unroll
  for (int e = 0; e < 8; ++e) { ex[e] = expf(acc[e] - m); s += ex[e]; }
  float inv = 1.f / s;
  float lse = m + logf(s);
  if (lane == 0) {
    tok_e[t] = bi;
    tok_p[t] = inv;
#pragma unroll
    for (int e = 0; e < 8; ++e) red[w][e] = ex[e] * inv;
    red[w][8] = lse * lse;
  }
  __syncthreads();
  if (tid < 9) {
    float v = red[0][tid] + red[1][tid] + red[2][tid] + red[3][tid];
    partials[tid * 2048 + blockIdx.x] = v;
  }
}

// ---------------- exact token-order scan + capacity + aux loss ----------------
__global__ __launch_bounds__(256) void kScan(
    const int* __restrict__ tok_e, const float* __restrict__ tok_p,
    const float* __restrict__ partials,
    int* __restrict__ tok_row, int* __restrict__ row2tok,
    float* __restrict__ row_prob, int* __restrict__ cnt_arr,
    float* __restrict__ aux_out) {
  __shared__ int sc[8][256];
  __shared__ float fr[256];
  __shared__ int tot[8];
  __shared__ float ps[9];
  int tid = threadIdx.x;
  int base = tid * 32;
  int lc[8];
#pragma unroll
  for (int e = 0; e < 8; ++e) lc[e] = 0;
  for (int j = 0; j < 32; ++j) lc[tok_e[base + j]]++;
#pragma unroll
  for (int e = 0; e < 8; ++e) sc[e][tid] = lc[e];
  __syncthreads();
  for (int s = 1; s < 256; s <<= 1) {
    int v[8];
#pragma unroll
    for (int e = 0; e < 8; ++e) v[e] = (tid >= s) ? sc[e][tid - s] : 0;
    __syncthreads();
#pragma unroll
    for (int e = 0; e < 8; ++e) sc[e][tid] += v[e];
    __syncthreads();
  }
  if (tid < 8) {
    tot[tid] = sc[tid][255];
    cnt_arr[tid] = min(sc[tid][255], 1024);
  }
  for (int c = 0; c < 9; ++c) {
    float sl = 0.f;
    for (int i = tid; i < 2048; i += 256) sl += partials[c * 2048 + i];
    fr[tid] = sl;
    __syncthreads();
    for (int s2 = 128; s2; s2 >>= 1) {
      if (tid < s2) fr[tid] += fr[tid + s2];
      __syncthreads();
    }
    if (tid == 0) ps[c] = fr[0];
    __syncthreads();
  }
  if (tid == 0) {
    float dot = 0.f;
#pragma unroll
    for (int e = 0; e < 8; ++e)
      dot += ((float)tot[e] / 8192.f) * (ps[e] / 8192.f);
    aux_out[0] = 0.01f * 8.f * dot + 0.001f * (ps[8] / 8192.f);
  }
  int run[8];
#pragma unroll
  for (int e = 0; e < 8; ++e) run[e] = sc[e][tid] - lc[e];
  for (int j = 0; j < 32; ++j) {
    int t = base + j;
    int e = tok_e[t];
    int p = run[e]++;
    if (p < 1024) {
      int row = e * 1024 + p;
      tok_row[t] = row;
      row2tok[row] = t;
      row_prob[row] = tok_p[t];
    } else {
      tok_row[t] = -1;
    }
  }
}

// ---------------- dispatch (bf16) + pass-through for dropped tokens ----------------
__global__ __launch_bounds__(256) void kDispatch(
    const float* __restrict__ x, const int* __restrict__ tok_row,
    u16* __restrict__ Xd, float* __restrict__ y) {
  int t = blockIdx.x, tid = threadIdx.x;
  int row = tok_row[t];
  float4 v = *(const float4*)&x[(size_t)t * 1024 + tid * 4];
  if (row >= 0) {
    ushort4 o;
    o.x = f2bf(v.x); o.y = f2bf(v.y); o.z = f2bf(v.z); o.w = f2bf(v.w);
    *(ushort4*)&Xd[(size_t)row * 1024 + tid * 4] = o;
  } else {
    *(float4*)&y[(size_t)t * 1024 + tid * 4] = v;
  }
}

// ---------------- transpose + fp32->bf16: [E][K][N] -> [E][N][K] ----------------
__global__ __launch_bounds__(256) void kTransConv(
    const float* __restrict__ src, u16* __restrict__ dst, int K, int N) {
  __shared__ u16 tl[64 * 66];
  int e = blockIdx.z;
  int n0 = blockIdx.x * 64, k0 = blockIdx.y * 64;
  src += (size_t)e * K * N;
  dst += (size_t)e * N * K;
  int tid = threadIdx.x;
  int rk = tid >> 4;
  int rn = (tid & 15) * 4;
#pragma unroll
  for (int j = 0; j < 4; ++j) {
    int k = rk + j * 16;
    float4 v = *(const float4*)&src[(size_t)(k0 + k) * N + n0 + rn];
    tl[(rn + 0) * 66 + k] = f2bf(v.x);
    tl[(rn + 1) * 66 + k] = f2bf(v.y);
    tl[(rn + 2) * 66 + k] = f2bf(v.z);
    tl[(rn + 3) * 66 + k] = f2bf(v.w);
  }
  __syncthreads();
  int f = tid >> 2;
  int seg = (tid & 3) * 16;
  uint4 tv[2];
  u16* tp = (u16*)tv;
#pragma unroll
  for (int i = 0; i < 16; ++i) tp[i] = tl[f * 66 + seg + i];
  *(uint4*)&dst[(size_t)(n0 + f) * K + k0 + seg] = tv[0];
  *(uint4*)&dst[(size_t)(n0 + f) * K + k0 + seg + 8] = tv[1];
}

// ---------------- 256x256x64 8-phase grouped TN GEMM (T2+T3+T4+T5) ----------------
// MODE 1: H = relu(A@B^T + b1) bf16.  MODE 2: fp32 partial (split-K=2) to Pout.
// LDS swizzle: slot(row,c16) holds global chunk (c16 ^ (row&7)); read at
// c16' = c16 ^ (row&7). Stage: linear dest + pre-swizzled per-lane global src.
// XCD-aware 1-D grid decode (T1): bid&7 = XCD (round-robin dispatch);
//   MODE1: e = bid&7 (expert per XCD), mt inner, nt outer -> B panel's 4
//          mt-blocks co-XCD + adjacent; A panels (2 MiB/expert) L2-resident.
//   MODE2: slab (e,kh) = 2 per XCD; mt inner within slab.

#define STA(BUF, U, KK) do {                                                       \
    int ra0_ = (U) * 64 + (tid >> 3);                                              \
    int ra1_ = 128 + ra0_;                                                         \
    gload16(Atb + (size_t)ra0_ * KD + (KK) + csw, &smA[BUF][ra0_ * 64 + dsl]);     \
    gload16(Atb + (size_t)ra1_ * KD + (KK) + csw, &smA[BUF][ra1_ * 64 + dsl]);     \
  } while (0)

#define BROW(RIDX, U) ((((RIDX) >> 5) * 64) + (U) * 32 + ((RIDX) & 31))
#define STB(BUF, U, KK) do {                                                       \
    int rb0_ = BROW(tid >> 3, U);                                                  \
    int rb1_ = BROW(64 + (tid >> 3), U);                                           \
    gload16(Btb + (size_t)rb0_ * KD + (KK) + csw, &smB[BUF][rb0_ * 64 + dsl]);     \
    gload16(Btb + (size_t)rb1_ * KD + (KK) + csw, &smB[BUF][rb1_ * 64 + dsl]);     \
  } while (0)

#define LDA(MB, BUF) do {                                                          \
    _Pragma("unroll") for (int m_ = 0; m_ < 4; ++m_)                               \
    _Pragma("unroll") for (int ks_ = 0; ks_ < 2; ++ks_)                            \
      av[m_][ks_] = *(const bf16x8*)&smA[BUF][(aro + ((MB) + m_) * 16) * 64 + cofs[ks_]]; \
  } while (0)

#define LDB(DST, NB, BUF) do {                                                     \
    _Pragma("unroll") for (int n_ = 0; n_ < 2; ++n_)                               \
    _Pragma("unroll") for (int ks_ = 0; ks_ < 2; ++ks_)                            \
      DST[n_][ks_] = *(const bf16x8*)&smB[BUF][(bro + ((NB) + n_) * 16) * 64 + cofs[ks_]]; \
  } while (0)

#define MFMAQ(MB, BV, NB) do {                                                     \
    _Pragma("unroll") for (int m_ = 0; m_ < 4; ++m_)                               \
    _Pragma("unroll") for (int n_ = 0; n_ < 2; ++n_)                               \
    _Pragma("unroll") for (int ks_ = 0; ks_ < 2; ++ks_)                            \
      acc[(MB) + m_][(NB) + n_] = __builtin_amdgcn_mfma_f32_16x16x32_bf16(         \
          av[m_][ks_], BV[n_][ks_], acc[(MB) + m_][(NB) + n_], 0, 0, 0);           \
  } while (0)

template <int MODE>
__global__ __launch_bounds__(512, 2) void kGemm8(
    const u16* __restrict__ A, const u16* __restrict__ Bw,
    const float* __restrict__ bias, u16* __restrict__ Hout,
    float* __restrict__ Pout, const int* __restrict__ cnt_arr) {
  constexpr int KD = (MODE == 1) ? 1024 : 4096;   // global K stride
  constexpr int ND = (MODE == 1) ? 4096 : 1024;
  constexpr int NT = (MODE == 1) ? 16 : 32;       // K-tiles (64) per block
  __shared__ u16 smA[2][16384];
  __shared__ u16 smB[2][16384];
  const int bid = blockIdx.x;
  int e, mt, nt, kh;
  if (MODE == 1) {
    e = bid & 7; mt = (bid >> 3) & 3; nt = bid >> 5; kh = 0;
  } else {
    int s = bid >> 3;
    int slab = ((bid & 7) << 1) | (s >> 4);
    e = slab >> 1; kh = slab & 1;
    mt = s & 3; nt = (s >> 2) & 3;
  }
  const int kbase = kh * 2048;
  const int cnt = cnt_arr[e];
  if (mt * 256 >= cnt) return;
  const int tid = threadIdx.x;
  const int lane = tid & 63, wid = tid >> 6;
  const int wr = wid >> 2, wc = wid & 3;
  const int lrow = lane & 15, kg = lane >> 4;
  const u16* Atb = A + (size_t)(e * 1024 + mt * 256) * KD + kbase;
  const u16* Btb = Bw + (size_t)e * ND * KD + (size_t)(nt * 256) * KD + kbase;
  const int csw = (((tid & 7) ^ ((tid >> 3) & 7))) * 8;  // swizzled src chunk (u16)
  const int dsl = (tid & 7) * 8;                         // linear dest chunk (u16)
  const int aro = wr * 128 + lrow;
  const int bro = wc * 64 + lrow;
  const int sw = lrow & 7;
  const int cofs[2] = { ((0 + kg) ^ sw) * 8, ((4 + kg) ^ sw) * 8 };

  f32x4 acc[8][4];
#pragma unroll
  for (int i = 0; i < 8; ++i)
#pragma unroll
    for (int j = 0; j < 4; ++j) acc[i][j] = (f32x4)0.f;
  bf16x8 av[4][2], b0[2][2], b1[2][2];

  // prologue: tile0 {A-lo,B-lo,B-hi,A-hi}, tile1 {A-lo,B-lo,B-hi} (A-hi at P1)
  STA(0, 0, 0); STB(0, 0, 0); STB(0, 1, 0); STA(0, 1, 0);
  STA(1, 0, 64); STB(1, 0, 64); STB(1, 1, 64);
  VMCNT6();
  BAR();

  for (int i = 0; i < NT / 2; ++i) {
    const int kc1 = (2 * i + 1) * 64;
    const int kn  = (2 * i + 2 < NT) ? (2 * i + 2) * 64 : 0;
    const int kn1 = (2 * i + 3 < NT) ? (2 * i + 3) * 64 : 0;
    // P1
    LDA(0, 0); LDB(b0, 0, 0);
    STA(1, 1, kc1);
    BAR(); LGKM0();
    PRIO1; MFMAQ(0, b0, 0); PRIO0;
    BAR();
    // P2
    LDB(b1, 2, 0);
    STA(0, 0, kn);
    BAR(); LGKM0();
    PRIO1; MFMAQ(0, b1, 2); PRIO0;
    BAR();
    // P3
    LDA(4, 0);
    STB(0, 0, kn);
    BAR(); LGKM0();
    PRIO1; MFMAQ(4, b0, 0); PRIO0;
    BAR();
    // P4
    STB(0, 1, kn);
    VMCNT6();
    BAR();
    PRIO1; MFMAQ(4, b1, 2); PRIO0;
    BAR();
    // P5
    LDA(0, 1); LDB(b0, 0, 1);
    STA(0, 1, kn);
    BAR(); LGKM0();
    PRIO1; MFMAQ(0, b0, 0); PRIO0;
    BAR();
    // P6
    LDB(b1, 2, 1);
    STA(1, 0, kn1);
    BAR(); LGKM0();
    PRIO1; MFMAQ(0, b1, 2); PRIO0;
    BAR();
    // P7
    LDA(4, 1);
    STB(1, 0, kn1);
    BAR(); LGKM0();
    PRIO1; MFMAQ(4, b0, 0); PRIO0;
    BAR();
    // P8
    STB(1, 1, kn1);
    VMCNT6();
    BAR();
    PRIO1; MFMAQ(4, b1, 2); PRIO0;
    BAR();
  }

  const int colb = nt * 256 + wc * 64 + lrow;
  if (MODE == 1) {
    float bv[4];
#pragma unroll
    for (int ni = 0; ni < 4; ++ni) bv[ni] = bias[e * 4096 + colb + ni * 16];
#pragma unroll
    for (int mi = 0; mi < 8; ++mi)
#pragma unroll
      for (int jj = 0; jj < 4; ++jj) {
        size_t rbase = (size_t)(e * 1024 + mt * 256 + wr * 128 + mi * 16 + kg * 4 + jj) * 4096;
#pragma unroll
        for (int ni = 0; ni < 4; ++ni)
          Hout[rbase + colb + ni * 16] = f2bf(fmaxf(acc[mi][ni][jj] + bv[ni], 0.f));
      }
  } else {
    float* P = Pout + (size_t)kh * 8388608;
#pragma unroll
    for (int mi = 0; mi < 8; ++mi)
#pragma unroll
      for (int jj = 0; jj < 4; ++jj) {
        size_t rbase = (size_t)(e * 1024 + mt * 256 + wr * 128 + mi * 16 + kg * 4 + jj) * 1024;
#pragma unroll
        for (int ni = 0; ni < 4; ++ni)
          P[rbase + colb + ni * 16] = acc[mi][ni][jj];
      }
  }
}

// ---------------- split-K combine: y[tok] = prob*(P0+P1+b2) ----------------
__global__ __launch_bounds__(256) void kCombine(
    const float* __restrict__ P0, const float* __restrict__ P1,
    const float* __restrict__ b2, const int* __restrict__ cnt_arr,
    const int* __restrict__ row2tok, const float* __restrict__ row_prob,
    float* __restrict__ y) {
  int r = blockIdx.x;
  int e = r >> 10, rie = r & 1023;
  if (rie >= cnt_arr[e]) return;
  int tok = row2tok[r];
  float pp = row_prob[r];
  int c = threadIdx.x * 4;
  float4 p0 = *(const float4*)&P0[(size_t)r * 1024 + c];
  float4 p1 = *(const float4*)&P1[(size_t)r * 1024 + c];
  float4 bb = *(const float4*)&b2[e * 1024 + c];
  float4 o;
  o.x = pp * (p0.x + p1.x + bb.x);
  o.y = pp * (p0.y + p1.y + bb.y);
  o.z = pp * (p0.z + p1.z + bb.z);
  o.w = pp * (p0.w + p1.w + bb.w);
  *(float4*)&y[(size_t)tok * 1024 + c] = o;
}

extern "C" void kernel_launch(void* const* d_in, const int* in_sizes, int n_in,
                              void* d_out, int out_size, void* d_ws, size_t ws_size,
                              hipStream_t stream) {
  (void)in_sizes; (void)n_in; (void)out_size; (void)ws_size;
  const float* x  = (const float*)d_in[0];
  const float* Wr = (const float*)d_in[1];
  const float* W1 = (const float*)d_in[2];
  const float* b1 = (const float*)d_in[3];
  const float* W2 = (const float*)d_in[4];
  const float* b2 = (const float*)d_in[5];
  float* y = (float*)d_out;
  char* ws = (char*)d_ws;
  u16*   W1T      = (u16*)(ws);                    // 64 MiB [E][4096][1024]; reused as P after GEMM1
  u16*   W2T      = (u16*)(ws + 67108864);         // 64 MiB [E][1024][4096]
  u16*   Xd       = (u16*)(ws + 134217728);        // 16 MiB
  u16*   H        = (u16*)(ws + 150994944);        // 64 MiB
  int*   tok_e    = (int*)(ws + 218103808);
  float* tok_p    = (float*)(ws + 218136576);
  int*   tok_row  = (int*)(ws + 218169344);
  int*   row2tok  = (int*)(ws + 218202112);
  float* row_prob = (float*)(ws + 218234880);
  int*   cnt_arr  = (int*)(ws + 218267648);
  float* partials = (float*)(ws + 218267776);
  float* Pbuf     = (float*)ws;                    // aliases W1T (dead after GEMM1)

  kRouter<<<2048, 256, 0, stream>>>(x, Wr, tok_e, tok_p, partials);
  kScan<<<1, 256, 0, stream>>>(tok_e, tok_p, partials, tok_row, row2tok,
                               row_prob, cnt_arr, y + 8388608);
  kDispatch<<<8192, 256, 0, stream>>>(x, tok_row, Xd, y);
  kTransConv<<<dim3(64, 16, 8), 256, 0, stream>>>(W1, W1T, 1024, 4096);
  kTransConv<<<dim3(16, 64, 8), 256, 0, stream>>>(W2, W2T, 4096, 1024);
  kGemm8<1><<<512, 512, 0, stream>>>(Xd, W1T, b1, H, nullptr, cnt_arr);
  kGemm8<2><<<256, 512, 0, stream>>>(H, W2T, nullptr, nullptr, Pbuf, cnt_arr);
  kCombine<<<8192, 256, 0, stream>>>(Pbuf, Pbuf + 8388608, b2, cnt_arr,
                                     row2tok, row_prob, y);
}